// Round 8
// baseline (304.695 us; speedup 1.0000x reference)
//
#include <hip/hip_runtime.h>
#include <hip/hip_fp16.h>
#include <math.h>

// EM routing, hardcoded geometry: CHILD_SPACE=12, K=3, S=1 -> P=10,
// CHILD_CAPS=16, PARENT_CAPS=O=32, POSE=16, N=4, KTOT=144
#define NB     4
#define P      10
#define P2     100
#define CS     12
#define CCAPS  16
#define KTOT   144
#define O      32
#define POSE   16
#define VSZ    73728          // KTOT*O*POSE elems per (b,p)
#define EPSF   1e-9f
#define LNF    22.2222222222222222f   // 100/(144/32)
#define TWO_PI 6.28318530717958647f
#define NBP    400
#define NKQ    3              // K-chunks per bp (V kernel)
#define KPU    48
#define SUNITS (NBP*NKQ)      // 1200
#define NCQ    2              // cc-split for CZ (8 cc per block)
#define CZG    (NB*CS*CS*NCQ) // 1152

#define LAM0 0.0005f          // 0.01*(1-0.95)
#define LAM1 0.000975f        // 0.01*(1-0.95^2)
#define LAM2 0.00142625f      // 0.01*(1-0.95^3)

__device__ float g_m1 [SUNITS*512];          // V partials
__device__ float g_m2 [SUNITS*512];
__device__ float g_sv [SUNITS*O];
__device__ float g_pm [NBP*9*NCQ*1024];      // CZ partials: m1[512] m2[512]
__device__ float g_ps [NBP*9*NCQ*32];
__device__ float g_mean[NBP*512];
__device__ float g_i2v [NBP*512];
__device__ float g_zpre[NBP*O];

// number of parents covering child coord x (1-D): min(x+1, 3, 12-x)
__device__ __forceinline__ int npar(int x) {
    int a = x + 1, b = CS - x;
    int m = a < 3 ? a : 3;
    return m < b ? m : b;
}

__device__ __forceinline__ void up8(uint4 u, float* f) {
    float2 a = __half22float2(*(__half2*)&u.x);
    float2 b = __half22float2(*(__half2*)&u.y);
    float2 c = __half22float2(*(__half2*)&u.z);
    float2 d = __half22float2(*(__half2*)&u.w);
    f[0] = a.x; f[1] = a.y; f[2] = b.x; f[3] = b.y;
    f[4] = c.x; f[5] = c.y; f[6] = d.x; f[7] = d.y;
}

// ---------------- V: fp32 stats (iter 0, closed-form rr) + fp16 convert ----
// grid 1200 = bp*3 + kq (48 k-rows). 256 thr: tid = ks*128 + q, q = o*4+c4.
__global__ __launch_bounds__(256)
void v_kernel(const float* __restrict__ votes, const float* __restrict__ acts,
              __half* __restrict__ hv)
{
    __shared__ float actl[KPU];
    __shared__ __align__(16) float rrp[KPU*O];
    __shared__ float4 lm1[256];
    __shared__ float4 lm2[256];
    __shared__ float  lss[256];

    const int tid = threadIdx.x;
    const int u   = blockIdx.x;
    const int bp  = u / NKQ;
    const int kq  = u - bp * NKQ;
    const int k0  = kq * KPU;
    const int ks  = tid >> 7;
    const int q   = tid & 127;
    const int o   = q >> 2;

    if (tid < KPU) actl[tid] = acts[bp * KTOT + k0 + tid];
    __syncthreads();

    for (int f = tid; f < KPU * O / 4; f += 256) {
        int kl = f >> 3;
        int kg = k0 + kl, kslot = kg >> 4;
        int kr = kslot / 3, kc = kslot - kr * 3;
        int p = bp % P2, pr = p / P, pc = p - pr * P;
        float ppc = (float)(npar(pr + kr) * npar(pc + kc));
        float r = actl[kl] / (ppc * 32.0f + EPSF);
        ((float4*)rrp)[f] = make_float4(r, r, r, r);
    }
    __syncthreads();

    const float* vb  = votes + (size_t)bp * VSZ + (size_t)(k0 + ks * 24) * 512 + q * 4;
    __half*      hb  = hv    + (size_t)bp * VSZ + (size_t)(k0 + ks * 24) * 512 + q * 4;
    const float* rr0 = rrp + (ks * 24) * O + o;
    float  s  = 0.f;
    float4 m1 = make_float4(0.f, 0.f, 0.f, 0.f);
    float4 m2 = make_float4(0.f, 0.f, 0.f, 0.f);
    #pragma unroll 8
    for (int i = 0; i < 24; ++i) {
        float  rp = rr0[i * O];
        float4 v  = *(const float4*)(vb + i * 512);
        s += rp;
        m1.x += rp * v.x;       m1.y += rp * v.y;
        m1.z += rp * v.z;       m1.w += rp * v.w;
        m2.x += rp * v.x * v.x; m2.y += rp * v.y * v.y;
        m2.z += rp * v.z * v.z; m2.w += rp * v.w * v.w;
        __half2 ha  = __floats2half2_rn(v.x, v.y);
        __half2 hbv = __floats2half2_rn(v.z, v.w);
        uint2 st;
        st.x = *(unsigned int*)&ha;
        st.y = *(unsigned int*)&hbv;
        *(uint2*)(hb + i * 512) = st;
    }
    lm1[tid] = m1; lm2[tid] = m2; lss[tid] = s;
    __syncthreads();

    if (tid < 128) {
        float4 a = lm1[tid], b = lm1[tid + 128];
        m1 = make_float4(a.x + b.x, a.y + b.y, a.z + b.z, a.w + b.w);
        a = lm2[tid]; b = lm2[tid + 128];
        m2 = make_float4(a.x + b.x, a.y + b.y, a.z + b.z, a.w + b.w);
        s = lss[tid] + lss[tid + 128];
        ((float4*)g_m1)[u * 128 + tid] = m1;
        ((float4*)g_m2)[u * 128 + tid] = m2;
        if ((tid & 3) == 0) g_sv[u * O + (tid >> 2)] = s;
    }
}

// ---------------- finish math from V partials (iter 0) ----------------
// 128 threads, all active. tid = o*4+c4.
__global__ __launch_bounds__(128)
void f0_kernel(const float* __restrict__ beta_v,
               const float* __restrict__ beta_a, float lam)
{
    __shared__ float costl[O];
    const int tid = threadIdx.x;
    const int o = tid >> 2, c4 = tid & 3;
    const int bp = blockIdx.x;

    float4 m1 = make_float4(0.f, 0.f, 0.f, 0.f);
    float4 m2 = make_float4(0.f, 0.f, 0.f, 0.f);
    float  s  = 0.f;
    #pragma unroll
    for (int j = 0; j < NKQ; ++j) {
        float4 a = ((const float4*)g_m1)[(bp * NKQ + j) * 128 + tid];
        float4 b = ((const float4*)g_m2)[(bp * NKQ + j) * 128 + tid];
        m1.x += a.x; m1.y += a.y; m1.z += a.z; m1.w += a.w;
        m2.x += b.x; m2.y += b.y; m2.z += b.z; m2.w += b.w;
        s += g_sv[(bp * NKQ + j) * O + o];
    }
    float denom = s + EPSF;
    float4 mean = make_float4(m1.x/denom, m1.y/denom, m1.z/denom, m1.w/denom);
    float4 var;
    var.x = fmaxf(m2.x/denom - mean.x*mean.x, 1e-30f);
    var.y = fmaxf(m2.y/denom - mean.y*mean.y, 1e-30f);
    var.z = fmaxf(m2.z/denom - mean.z*mean.z, 1e-30f);
    var.w = fmaxf(m2.w/denom - mean.w*mean.w, 1e-30f);
    float4 i2 = make_float4(0.5f/var.x, 0.5f/var.y, 0.5f/var.z, 0.5f/var.w);
    float lve = logf(var.x+EPSF)+logf(var.y+EPSF)+logf(var.z+EPSF)+logf(var.w+EPSF);
    float lv2 = logf(TWO_PI*var.x)+logf(TWO_PI*var.y)+logf(TWO_PI*var.z)+logf(TWO_PI*var.w);
    lve += __shfl_xor(lve,1); lve += __shfl_xor(lve,2);
    lv2 += __shfl_xor(lv2,1); lv2 += __shfl_xor(lv2,2);
    if (c4 == 0) costl[o] = (16.f*beta_v[o] + 0.5f*lve) * s * LNF;
    __syncthreads();
    float cm = 0.f;
    #pragma unroll
    for (int i = 0; i < O; ++i) cm += costl[i];
    cm *= (1.f/32.f);
    float sq = 0.f;
    #pragma unroll
    for (int i = 0; i < O; ++i) { float d = costl[i]-cm; sq += d*d; }
    float cstd = sqrtf(sq * (1.f/32.f));
    float aj = 1.f/(1.f+expf(-lam*(beta_a[o] + (cm-costl[o])/(cstd+EPSF))));
    ((float4*)g_mean)[bp*128+tid] = mean;
    ((float4*)g_i2v)[bp*128+tid]  = i2;
    if (c4 == 0) g_zpre[bp*O+o] = logf(aj+EPSF) - 0.5f*lv2;
}

// ---------------- CZ: child-centric fused e_step + next-iter stats --------
// grid 1152 = (b*144 + child)*2 + ccq. 256 thr: tid = ccl*32 + o, cc=ccq*8+ccl.
// zz computed in regs; softmax local (per (cc): over 9 si x 32 o);
// stats partials per (parent,si,ccq) slab -> g_pm / g_ps (no atomics).
__global__ __launch_bounds__(256)
void cz_kernel(const __half* __restrict__ hv, const float* __restrict__ acts)
{
    __shared__ float red[4*32*33];   // [wave][o][m1(16) m2(16) s]

    const int tid = threadIdx.x;
    const int ccl = tid >> 5;
    const int o   = tid & 31;
    const int blk = blockIdx.x;
    const int ccq = blk & (NCQ-1);
    const int bc  = blk / NCQ;
    const int b   = bc / (CS*CS);
    const int c   = bc - b*(CS*CS);
    const int cr  = c / CS, cl = c - cr*CS;
    const int cc  = ccq*8 + ccl;

    int   bpps[9];
    float ez[9];
    float av[9];
    float vmax = -1e30f;

    // phase 1: zz
    #pragma unroll
    for (int kr = 0; kr < 3; ++kr) {
        #pragma unroll
        for (int kc = 0; kc < 3; ++kc) {
            const int si  = kr*3 + kc;
            const int pr_ = cr - kr, pc_ = cl - kc;
            const bool ok = (pr_ >= 0 && pr_ < P && pc_ >= 0 && pc_ < P);
            int bpp = ok ? (b*P2 + pr_*P + pc_) : -1;
            bpps[si] = bpp;
            float z = -1e30f;
            if (ok) {
                const __half* vb = hv + (size_t)bpp*VSZ + (size_t)(si*16+cc)*512 + o*16;
                uint4 u0 = *(const uint4*)(vb);
                uint4 u1 = *(const uint4*)(vb + 8);
                float f[16]; up8(u0, f); up8(u1, f + 8);
                const float4* mm = (const float4*)(g_mean + (size_t)bpp*512 + o*16);
                const float4* iv = (const float4*)(g_i2v  + (size_t)bpp*512 + o*16);
                float t = 0.f;
                #pragma unroll
                for (int j4 = 0; j4 < 4; ++j4) {
                    float4 m = mm[j4], w = iv[j4];
                    float d0 = f[j4*4  ]-m.x, d1 = f[j4*4+1]-m.y;
                    float d2 = f[j4*4+2]-m.z, d3 = f[j4*4+3]-m.w;
                    t += d0*d0*w.x + d1*d1*w.y + d2*d2*w.z + d3*d3*w.w;
                }
                z = g_zpre[bpp*O + o] - t;
                av[si] = acts[bpp*KTOT + si*16 + cc];
            }
            ez[si] = z;
            vmax = fmaxf(vmax, z);
        }
    }
    // softmax over (si, o) per cc
    vmax = fmaxf(vmax, __shfl_xor(vmax, 1));
    vmax = fmaxf(vmax, __shfl_xor(vmax, 2));
    vmax = fmaxf(vmax, __shfl_xor(vmax, 4));
    vmax = fmaxf(vmax, __shfl_xor(vmax, 8));
    vmax = fmaxf(vmax, __shfl_xor(vmax, 16));
    float ps = 0.f;
    #pragma unroll
    for (int si = 0; si < 9; ++si) {
        float e = (ez[si] > -1e29f) ? expf(ez[si] - vmax) : 0.f;
        ez[si] = e;
        ps += e;
    }
    ps += __shfl_xor(ps, 1);
    ps += __shfl_xor(ps, 2);
    ps += __shfl_xor(ps, 4);
    ps += __shfl_xor(ps, 8);
    ps += __shfl_xor(ps, 16);
    const float inv = 1.f / ps;

    // phase 2: per-si stats partial -> slab (validity is block-uniform)
    #pragma unroll
    for (int si = 0; si < 9; ++si) {
        const int bpp = bpps[si];
        if (bpp >= 0) {
            float rp = ez[si] * inv * av[si];
            const __half* vb = hv + (size_t)bpp*VSZ + (size_t)(si*16+cc)*512 + o*16;
            uint4 u0 = *(const uint4*)(vb);
            uint4 u1 = *(const uint4*)(vb + 8);
            float f[16]; up8(u0, f); up8(u1, f + 8);
            float m1[16], m2[16];
            #pragma unroll
            for (int j = 0; j < 16; ++j) { m1[j] = rp*f[j]; m2[j] = rp*f[j]*f[j]; }
            float s = rp;
            #pragma unroll
            for (int j = 0; j < 16; ++j) {
                m1[j] += __shfl_xor(m1[j], 32);
                m2[j] += __shfl_xor(m2[j], 32);
            }
            s += __shfl_xor(s, 32);
            if ((ccl & 1) == 0) {
                float* r = red + ((ccl >> 1)*32 + o)*33;
                #pragma unroll
                for (int j = 0; j < 16; ++j) { r[j] = m1[j]; r[16+j] = m2[j]; }
                r[32] = s;
            }
            __syncthreads();
            if (tid < 32) {
                float* dst = g_pm + ((size_t)(bpp*9 + si)*NCQ + ccq)*1024;
                float sa = 0.f;
                #pragma unroll
                for (int j4 = 0; j4 < 8; ++j4) {
                    float4 acc = make_float4(0.f, 0.f, 0.f, 0.f);
                    #pragma unroll
                    for (int w = 0; w < 4; ++w) {
                        const float* r = red + (w*32 + tid)*33 + j4*4;
                        acc.x += r[0]; acc.y += r[1]; acc.z += r[2]; acc.w += r[3];
                    }
                    int half = j4 >> 2, j4l = j4 & 3;   // 0..3 -> m1, 4..7 -> m2
                    ((float4*)(dst + half*512))[tid*4 + j4l] = acc;
                }
                #pragma unroll
                for (int w = 0; w < 4; ++w) sa += red[(w*32 + tid)*33 + 32];
                g_ps[((bpp*9 + si)*NCQ + ccq)*32 + tid] = sa;
            }
            __syncthreads();
        }
    }
}

// ---------------- F12: finish from CZ slabs ----------------
template<bool LAST>
__global__ __launch_bounds__(128)
void f12_kernel(const float* __restrict__ beta_v,
                const float* __restrict__ beta_a,
                float* __restrict__ out, float lam)
{
    __shared__ float costl[O];
    const int tid = threadIdx.x;
    const int o = tid >> 2, c4 = tid & 3;
    const int bp = blockIdx.x;

    float4 m1 = make_float4(0.f, 0.f, 0.f, 0.f);
    float4 m2 = make_float4(0.f, 0.f, 0.f, 0.f);
    float  s  = 0.f;
    #pragma unroll
    for (int si = 0; si < 9; ++si) {
        #pragma unroll
        for (int qq = 0; qq < NCQ; ++qq) {
            const float* base = g_pm + ((size_t)(bp*9 + si)*NCQ + qq)*1024;
            float4 a = ((const float4*)base)[tid];
            float4 b = ((const float4*)(base + 512))[tid];
            m1.x += a.x; m1.y += a.y; m1.z += a.z; m1.w += a.w;
            m2.x += b.x; m2.y += b.y; m2.z += b.z; m2.w += b.w;
            s += g_ps[((bp*9 + si)*NCQ + qq)*32 + o];
        }
    }
    float denom = s + EPSF;
    float4 mean = make_float4(m1.x/denom, m1.y/denom, m1.z/denom, m1.w/denom);
    float4 var;
    var.x = fmaxf(m2.x/denom - mean.x*mean.x, 1e-30f);
    var.y = fmaxf(m2.y/denom - mean.y*mean.y, 1e-30f);
    var.z = fmaxf(m2.z/denom - mean.z*mean.z, 1e-30f);
    var.w = fmaxf(m2.w/denom - mean.w*mean.w, 1e-30f);
    float4 i2 = make_float4(0.5f/var.x, 0.5f/var.y, 0.5f/var.z, 0.5f/var.w);
    float lve = logf(var.x+EPSF)+logf(var.y+EPSF)+logf(var.z+EPSF)+logf(var.w+EPSF);
    float lv2 = logf(TWO_PI*var.x)+logf(TWO_PI*var.y)+logf(TWO_PI*var.z)+logf(TWO_PI*var.w);
    lve += __shfl_xor(lve,1); lve += __shfl_xor(lve,2);
    lv2 += __shfl_xor(lv2,1); lv2 += __shfl_xor(lv2,2);
    if (c4 == 0) costl[o] = (16.f*beta_v[o] + 0.5f*lve) * s * LNF;
    __syncthreads();
    float cm = 0.f;
    #pragma unroll
    for (int i = 0; i < O; ++i) cm += costl[i];
    cm *= (1.f/32.f);
    float sq = 0.f;
    #pragma unroll
    for (int i = 0; i < O; ++i) { float d = costl[i]-cm; sq += d*d; }
    float cstd = sqrtf(sq * (1.f/32.f));
    float aj = 1.f/(1.f+expf(-lam*(beta_a[o] + (cm-costl[o])/(cstd+EPSF))));

    if (LAST) {
        ((float4*)out)[bp*128 + tid] = mean;
        if (c4 == 0) out[(size_t)NBP*512 + bp*O + o] = aj;
    } else {
        ((float4*)g_mean)[bp*128 + tid] = mean;
        ((float4*)g_i2v)[bp*128 + tid]  = i2;
        if (c4 == 0) g_zpre[bp*O + o] = logf(aj+EPSF) - 0.5f*lv2;
    }
}

extern "C" void kernel_launch(void* const* d_in, const int* in_sizes, int n_in,
                              void* d_out, int out_size, void* d_ws, size_t ws_size,
                              hipStream_t stream)
{
    (void)in_sizes; (void)n_in; (void)out_size; (void)ws_size;

    const float* votes = (const float*)d_in[0];
    const float* acts  = (const float*)d_in[1];
    const float* bv    = (const float*)d_in[2];
    const float* ba    = (const float*)d_in[3];
    float* out = (float*)d_out;
    __half* hv = (__half*)d_ws;          // 59 MB fp16 votes copy

    v_kernel<<<dim3(SUNITS), dim3(256), 0, stream>>>(votes, acts, hv);
    f0_kernel<<<dim3(NBP), dim3(128), 0, stream>>>(bv, ba, LAM0);
    cz_kernel<<<dim3(CZG), dim3(256), 0, stream>>>(hv, acts);
    f12_kernel<false><<<dim3(NBP), dim3(128), 0, stream>>>(bv, ba, out, LAM1);
    cz_kernel<<<dim3(CZG), dim3(256), 0, stream>>>(hv, acts);
    f12_kernel<true ><<<dim3(NBP), dim3(128), 0, stream>>>(bv, ba, out, LAM2);
}

// Round 9
// 271.833 us; speedup vs baseline: 1.1209x; 1.1209x over previous
//
#include <hip/hip_runtime.h>
#include <hip/hip_fp16.h>
#include <math.h>

// EM routing, hardcoded geometry: CHILD_SPACE=12, K=3, S=1 -> P=10,
// CHILD_CAPS=16, PARENT_CAPS=O=32, POSE=16, N=4, KTOT=144
#define NB     4
#define P      10
#define P2     100
#define CS     12
#define CCAPS  16
#define KTOT   144
#define O      32
#define POSE   16
#define VSZ    73728          // KTOT*O*POSE elems per (b,p)
#define EPSF   1e-9f
#define LNF    22.2222222222222222f   // 100/(144/32)
#define TWO_PI 6.28318530717958647f
#define NBP    400
#define NKQ    3              // K-chunks per bp (stats kernels)
#define KPU    48
#define SUNITS (NBP*NKQ)      // 1200
#define NCQ    2              // cc-split for CZ (8 cc per block)
#define CZG    (NB*CS*CS*NCQ) // 1152

#define LAM0 0.0005f          // 0.01*(1-0.95)
#define LAM1 0.000975f        // 0.01*(1-0.95^2)
#define LAM2 0.00142625f      // 0.01*(1-0.95^3)

__device__ float g_m1 [SUNITS*512];          // stats partials (V and S16)
__device__ float g_m2 [SUNITS*512];
__device__ float g_sv [SUNITS*O];
__device__ float g_rrp[NBP*KTOT*O];          // rr' = rr * act (CZ output)
__device__ float g_mean[NBP*512];
__device__ float g_i2v [NBP*512];
__device__ float g_zpre[NBP*O];

// number of parents covering child coord x (1-D): min(x+1, 3, 12-x)
__device__ __forceinline__ int npar(int x) {
    int a = x + 1, b = CS - x;
    int m = a < 3 ? a : 3;
    return m < b ? m : b;
}

__device__ __forceinline__ void up8(uint4 u, float* f) {
    float2 a = __half22float2(*(__half2*)&u.x);
    float2 b = __half22float2(*(__half2*)&u.y);
    float2 c = __half22float2(*(__half2*)&u.z);
    float2 d = __half22float2(*(__half2*)&u.w);
    f[0] = a.x; f[1] = a.y; f[2] = b.x; f[3] = b.y;
    f[4] = c.x; f[5] = c.y; f[6] = d.x; f[7] = d.y;
}

// ---------------- V: fp32 stats (iter 0, closed-form rr) + fp16 convert ----
// grid 1200 = bp*3 + kq (48 k-rows). 256 thr: tid = ks*128 + q, q = o*4+c4.
__global__ __launch_bounds__(256)
void v_kernel(const float* __restrict__ votes, const float* __restrict__ acts,
              __half* __restrict__ hv)
{
    __shared__ float actl[KPU];
    __shared__ __align__(16) float rrp[KPU*O];
    __shared__ float4 lm1[256];
    __shared__ float4 lm2[256];
    __shared__ float  lss[256];

    const int tid = threadIdx.x;
    const int u   = blockIdx.x;
    const int bp  = u / NKQ;
    const int kq  = u - bp * NKQ;
    const int k0  = kq * KPU;
    const int ks  = tid >> 7;
    const int q   = tid & 127;
    const int o   = q >> 2;

    if (tid < KPU) actl[tid] = acts[bp * KTOT + k0 + tid];
    __syncthreads();

    for (int f = tid; f < KPU * O / 4; f += 256) {
        int kl = f >> 3;
        int kg = k0 + kl, kslot = kg >> 4;
        int kr = kslot / 3, kc = kslot - kr * 3;
        int p = bp % P2, pr = p / P, pc = p - pr * P;
        float ppc = (float)(npar(pr + kr) * npar(pc + kc));
        float r = actl[kl] / (ppc * 32.0f + EPSF);
        ((float4*)rrp)[f] = make_float4(r, r, r, r);
    }
    __syncthreads();

    const float* vb  = votes + (size_t)bp * VSZ + (size_t)(k0 + ks * 24) * 512 + q * 4;
    __half*      hb  = hv    + (size_t)bp * VSZ + (size_t)(k0 + ks * 24) * 512 + q * 4;
    const float* rr0 = rrp + (ks * 24) * O + o;
    float  s  = 0.f;
    float4 m1 = make_float4(0.f, 0.f, 0.f, 0.f);
    float4 m2 = make_float4(0.f, 0.f, 0.f, 0.f);
    #pragma unroll 8
    for (int i = 0; i < 24; ++i) {
        float  rp = rr0[i * O];
        float4 v  = *(const float4*)(vb + i * 512);
        s += rp;
        m1.x += rp * v.x;       m1.y += rp * v.y;
        m1.z += rp * v.z;       m1.w += rp * v.w;
        m2.x += rp * v.x * v.x; m2.y += rp * v.y * v.y;
        m2.z += rp * v.z * v.z; m2.w += rp * v.w * v.w;
        __half2 ha  = __floats2half2_rn(v.x, v.y);
        __half2 hbv = __floats2half2_rn(v.z, v.w);
        uint2 st;
        st.x = *(unsigned int*)&ha;
        st.y = *(unsigned int*)&hbv;
        *(uint2*)(hb + i * 512) = st;
    }
    lm1[tid] = m1; lm2[tid] = m2; lss[tid] = s;
    __syncthreads();

    if (tid < 128) {
        float4 a = lm1[tid], b = lm1[tid + 128];
        m1 = make_float4(a.x + b.x, a.y + b.y, a.z + b.z, a.w + b.w);
        a = lm2[tid]; b = lm2[tid + 128];
        m2 = make_float4(a.x + b.x, a.y + b.y, a.z + b.z, a.w + b.w);
        s = lss[tid] + lss[tid + 128];
        ((float4*)g_m1)[u * 128 + tid] = m1;
        ((float4*)g_m2)[u * 128 + tid] = m2;
        if ((tid & 3) == 0) g_sv[u * O + (tid >> 2)] = s;
    }
}

// ---------------- S16: stats partials from fp16 votes + rr' ----------------
// 256 thr: tid = ks*64 + qp, qp = o*2 + h; thread owns 8 pose comps (uint4).
__global__ __launch_bounds__(256)
void s16_kernel(const __half* __restrict__ hv)
{
    __shared__ __align__(16) float rrp[KPU*O];    // 6 KB
    __shared__ float4 lm1[512];                    // 8 KB
    __shared__ float4 lm2[512];                    // 8 KB
    __shared__ float  lss[256];

    const int tid = threadIdx.x;
    const int u   = blockIdx.x;
    const int bp  = u / NKQ;
    const int kq  = u - bp * NKQ;
    const int k0  = kq * KPU;
    const int ks  = tid >> 6;
    const int qp  = tid & 63;
    const int o   = qp >> 1;

    for (int f = tid; f < KPU * O / 4; f += 256)
        ((float4*)rrp)[f] = ((const float4*)(g_rrp + (size_t)bp * (KTOT * O) + k0 * O))[f];
    __syncthreads();

    const __half* vb = hv + (size_t)bp * VSZ + (size_t)(k0 + ks * 12) * 512 + qp * 8;
    const float* rr0 = rrp + (ks * 12) * O + o;
    float s = 0.f;
    float m1[8], m2[8];
    #pragma unroll
    for (int j = 0; j < 8; ++j) { m1[j] = 0.f; m2[j] = 0.f; }
    #pragma unroll 4
    for (int i = 0; i < 12; ++i) {
        float rp = rr0[i * O];
        uint4 u4 = *(const uint4*)(vb + i * 512);
        float f[8]; up8(u4, f);
        s += rp;
        #pragma unroll
        for (int j = 0; j < 8; ++j) {
            m1[j] += rp * f[j];
            m2[j] += rp * f[j] * f[j];
        }
    }
    lm1[tid*2]   = make_float4(m1[0], m1[1], m1[2], m1[3]);
    lm1[tid*2+1] = make_float4(m1[4], m1[5], m1[6], m1[7]);
    lm2[tid*2]   = make_float4(m2[0], m2[1], m2[2], m2[3]);
    lm2[tid*2+1] = make_float4(m2[4], m2[5], m2[6], m2[7]);
    lss[tid] = s;
    __syncthreads();

    if (tid < 64) {
        #pragma unroll
        for (int j = 0; j < 2; ++j) {
            float4 a0 = lm1[(tid)*2+j],       a1 = lm1[(64+tid)*2+j];
            float4 a2 = lm1[(128+tid)*2+j],   a3 = lm1[(192+tid)*2+j];
            float4 r = make_float4(a0.x+a1.x+a2.x+a3.x, a0.y+a1.y+a2.y+a3.y,
                                   a0.z+a1.z+a2.z+a3.z, a0.w+a1.w+a2.w+a3.w);
            ((float4*)g_m1)[u * 128 + tid*2 + j] = r;
            float4 b0 = lm2[(tid)*2+j],       b1 = lm2[(64+tid)*2+j];
            float4 b2 = lm2[(128+tid)*2+j],   b3 = lm2[(192+tid)*2+j];
            float4 r2 = make_float4(b0.x+b1.x+b2.x+b3.x, b0.y+b1.y+b2.y+b3.y,
                                    b0.z+b1.z+b2.z+b3.z, b0.w+b1.w+b2.w+b3.w);
            ((float4*)g_m2)[u * 128 + tid*2 + j] = r2;
        }
        float sr = lss[tid] + lss[64+tid] + lss[128+tid] + lss[192+tid];
        if ((tid & 1) == 0) g_sv[u * O + (tid >> 1)] = sr;
    }
}

// ---------------- F: finish from partial slabs ----------------
// grid 400, 128 threads, tid = o*4 + c4.
template<bool LAST>
__global__ __launch_bounds__(128)
void f_kernel(const float* __restrict__ beta_v,
              const float* __restrict__ beta_a,
              float* __restrict__ out, float lam)
{
    __shared__ float costl[O];
    const int tid = threadIdx.x;
    const int o = tid >> 2, c4 = tid & 3;
    const int bp = blockIdx.x;

    float4 m1 = make_float4(0.f, 0.f, 0.f, 0.f);
    float4 m2 = make_float4(0.f, 0.f, 0.f, 0.f);
    float  s  = 0.f;
    #pragma unroll
    for (int j = 0; j < NKQ; ++j) {
        float4 a = ((const float4*)g_m1)[(bp * NKQ + j) * 128 + tid];
        float4 b = ((const float4*)g_m2)[(bp * NKQ + j) * 128 + tid];
        m1.x += a.x; m1.y += a.y; m1.z += a.z; m1.w += a.w;
        m2.x += b.x; m2.y += b.y; m2.z += b.z; m2.w += b.w;
        s += g_sv[(bp * NKQ + j) * O + o];
    }
    float denom = s + EPSF;
    float4 mean = make_float4(m1.x/denom, m1.y/denom, m1.z/denom, m1.w/denom);
    float4 var;
    var.x = fmaxf(m2.x/denom - mean.x*mean.x, 1e-30f);
    var.y = fmaxf(m2.y/denom - mean.y*mean.y, 1e-30f);
    var.z = fmaxf(m2.z/denom - mean.z*mean.z, 1e-30f);
    var.w = fmaxf(m2.w/denom - mean.w*mean.w, 1e-30f);
    float4 i2 = make_float4(0.5f/var.x, 0.5f/var.y, 0.5f/var.z, 0.5f/var.w);
    float lve = logf(var.x+EPSF)+logf(var.y+EPSF)+logf(var.z+EPSF)+logf(var.w+EPSF);
    float lv2 = logf(TWO_PI*var.x)+logf(TWO_PI*var.y)+logf(TWO_PI*var.z)+logf(TWO_PI*var.w);
    lve += __shfl_xor(lve,1); lve += __shfl_xor(lve,2);
    lv2 += __shfl_xor(lv2,1); lv2 += __shfl_xor(lv2,2);
    if (c4 == 0) costl[o] = (16.f*beta_v[o] + 0.5f*lve) * s * LNF;
    __syncthreads();
    float cm = 0.f;
    #pragma unroll
    for (int i = 0; i < O; ++i) cm += costl[i];
    cm *= (1.f/32.f);
    float sq = 0.f;
    #pragma unroll
    for (int i = 0; i < O; ++i) { float d = costl[i]-cm; sq += d*d; }
    float cstd = sqrtf(sq * (1.f/32.f));
    float aj = 1.f/(1.f+expf(-lam*(beta_a[o] + (cm-costl[o])/(cstd+EPSF))));

    if (LAST) {
        ((float4*)out)[bp*128 + tid] = mean;
        if (c4 == 0) out[(size_t)NBP*512 + bp*O + o] = aj;
    } else {
        ((float4*)g_mean)[bp*128 + tid] = mean;
        ((float4*)g_i2v)[bp*128 + tid]  = i2;
        if (c4 == 0) g_zpre[bp*O + o] = logf(aj+EPSF) - 0.5f*lv2;
    }
}

// ---------------- CZ: child-centric fused zz + segment softmax ------------
// grid 1152 = (b*144 + child)*2 + ccq. 256 thr: tid = ccl*32 + o, cc=ccq*8+ccl.
// Computes zz in regs, softmax over (9 si, 32 o) per cc, writes rr' = rr*act.
__global__ __launch_bounds__(256)
void cz_kernel(const __half* __restrict__ hv, const float* __restrict__ acts)
{
    const int tid = threadIdx.x;
    const int ccl = tid >> 5;
    const int o   = tid & 31;
    const int blk = blockIdx.x;
    const int ccq = blk & (NCQ-1);
    const int bc  = blk / NCQ;
    const int b   = bc / (CS*CS);
    const int c   = bc - b*(CS*CS);
    const int cr  = c / CS, cl = c - cr*CS;
    const int cc  = ccq*8 + ccl;

    int   bpps[9];
    float ez[9];
    float av[9];
    float vmax = -1e30f;

    #pragma unroll
    for (int kr = 0; kr < 3; ++kr) {
        #pragma unroll
        for (int kc = 0; kc < 3; ++kc) {
            const int si  = kr*3 + kc;
            const int pr_ = cr - kr, pc_ = cl - kc;
            const bool ok = (pr_ >= 0 && pr_ < P && pc_ >= 0 && pc_ < P);
            int bpp = ok ? (b*P2 + pr_*P + pc_) : -1;
            bpps[si] = bpp;
            float z = -1e30f;
            av[si] = 0.f;
            if (ok) {
                const __half* vb = hv + (size_t)bpp*VSZ + (size_t)(si*16+cc)*512 + o*16;
                uint4 u0 = *(const uint4*)(vb);
                uint4 u1 = *(const uint4*)(vb + 8);
                float f[16]; up8(u0, f); up8(u1, f + 8);
                const float4* mm = (const float4*)(g_mean + (size_t)bpp*512 + o*16);
                const float4* iv = (const float4*)(g_i2v  + (size_t)bpp*512 + o*16);
                float t = 0.f;
                #pragma unroll
                for (int j4 = 0; j4 < 4; ++j4) {
                    float4 m = mm[j4], w = iv[j4];
                    float d0 = f[j4*4  ]-m.x, d1 = f[j4*4+1]-m.y;
                    float d2 = f[j4*4+2]-m.z, d3 = f[j4*4+3]-m.w;
                    t += d0*d0*w.x + d1*d1*w.y + d2*d2*w.z + d3*d3*w.w;
                }
                z = g_zpre[bpp*O + o] - t;
                av[si] = acts[bpp*KTOT + si*16 + cc];
            }
            ez[si] = z;
            vmax = fmaxf(vmax, z);
        }
    }
    // softmax over (si, o) per cc
    vmax = fmaxf(vmax, __shfl_xor(vmax, 1));
    vmax = fmaxf(vmax, __shfl_xor(vmax, 2));
    vmax = fmaxf(vmax, __shfl_xor(vmax, 4));
    vmax = fmaxf(vmax, __shfl_xor(vmax, 8));
    vmax = fmaxf(vmax, __shfl_xor(vmax, 16));
    float ps = 0.f;
    #pragma unroll
    for (int si = 0; si < 9; ++si) {
        float e = (ez[si] > -1e29f) ? expf(ez[si] - vmax) : 0.f;
        ez[si] = e;
        ps += e;
    }
    ps += __shfl_xor(ps, 1);
    ps += __shfl_xor(ps, 2);
    ps += __shfl_xor(ps, 4);
    ps += __shfl_xor(ps, 8);
    ps += __shfl_xor(ps, 16);
    const float inv = 1.f / ps;

    #pragma unroll
    for (int si = 0; si < 9; ++si) {
        const int bpp = bpps[si];
        if (bpp >= 0)
            g_rrp[((size_t)bpp*KTOT + si*16 + cc)*32 + o] = ez[si] * inv * av[si];
    }
}

extern "C" void kernel_launch(void* const* d_in, const int* in_sizes, int n_in,
                              void* d_out, int out_size, void* d_ws, size_t ws_size,
                              hipStream_t stream)
{
    (void)in_sizes; (void)n_in; (void)out_size; (void)ws_size;

    const float* votes = (const float*)d_in[0];
    const float* acts  = (const float*)d_in[1];
    const float* bv    = (const float*)d_in[2];
    const float* ba    = (const float*)d_in[3];
    float* out = (float*)d_out;
    __half* hv = (__half*)d_ws;          // 59 MB fp16 votes copy

    v_kernel<<<dim3(SUNITS), dim3(256), 0, stream>>>(votes, acts, hv);
    f_kernel<false><<<dim3(NBP), dim3(128), 0, stream>>>(bv, ba, out, LAM0);
    cz_kernel<<<dim3(CZG), dim3(256), 0, stream>>>(hv, acts);
    s16_kernel<<<dim3(SUNITS), dim3(256), 0, stream>>>(hv);
    f_kernel<false><<<dim3(NBP), dim3(128), 0, stream>>>(bv, ba, out, LAM1);
    cz_kernel<<<dim3(CZG), dim3(256), 0, stream>>>(hv, acts);
    s16_kernel<<<dim3(SUNITS), dim3(256), 0, stream>>>(hv);
    f_kernel<true ><<<dim3(NBP), dim3(128), 0, stream>>>(bv, ba, out, LAM2);
}

// Round 10
// 263.686 us; speedup vs baseline: 1.1555x; 1.0309x over previous
//
#include <hip/hip_runtime.h>
#include <hip/hip_fp16.h>
#include <math.h>

// EM routing, hardcoded geometry: CHILD_SPACE=12, K=3, S=1 -> P=10,
// CHILD_CAPS=16, PARENT_CAPS=O=32, POSE=16, N=4, KTOT=144
#define NB     4
#define P      10
#define P2     100
#define CS     12
#define CCAPS  16
#define KTOT   144
#define O      32
#define POSE   16
#define VSZ    73728          // KTOT*O*POSE elems per (b,p)
#define EPSF   1e-9f
#define LNF    22.2222222222222222f   // 100/(144/32)
#define TWO_PI 6.28318530717958647f
#define NBP    400
#define NKQ    3              // K-chunks per bp
#define KPU    48
#define SUNITS (NBP*NKQ)      // 1200
#define EUNITS (NB*CS*CS*2)   // 1152

#define LAM0 0.0005f          // 0.01*(1-0.95)
#define LAM1 0.000975f        // 0.01*(1-0.95^2)
#define LAM2 0.00142625f      // 0.01*(1-0.95^3)

__device__ float g_rr [NBP*KTOT*O];
__device__ float g_zz [NBP*KTOT*O];
__device__ float g_m1 [SUNITS*512];
__device__ float g_m2 [SUNITS*512];
__device__ float g_sv [SUNITS*O];

// number of parents covering child coord x (1-D): min(x+1, 3, 12-x)
__device__ __forceinline__ int npar(int x) {
    int a = x + 1, b = CS - x;
    int m = a < 3 ? a : 3;
    return m < b ? m : b;
}

__device__ __forceinline__ void up8(uint4 u, float* f) {
    float2 a = __half22float2(*(__half2*)&u.x);
    float2 b = __half22float2(*(__half2*)&u.y);
    float2 c = __half22float2(*(__half2*)&u.z);
    float2 d = __half22float2(*(__half2*)&u.w);
    f[0] = a.x; f[1] = a.y; f[2] = b.x; f[3] = b.y;
    f[4] = c.x; f[5] = c.y; f[6] = d.x; f[7] = d.y;
}

// ---------------- V: fp32 stats (iter 0, closed-form rr) + fp16 convert ----
// grid 1200 = bp*3 + kq (48 k-rows). 256 thr: tid = ks*128 + q, q = o*4+c4.
// MLP fix: double-buffered batches of 8 float4 loads kept live in registers.
__global__ __launch_bounds__(256)
void v_kernel(const float* __restrict__ votes, const float* __restrict__ acts,
              __half* __restrict__ hv)
{
    __shared__ float actl[KPU];
    __shared__ __align__(16) float rrp[KPU*O];
    __shared__ float4 lm1[256];
    __shared__ float4 lm2[256];
    __shared__ float  lss[256];

    const int tid = threadIdx.x;
    const int u   = blockIdx.x;
    const int bp  = u / NKQ;
    const int kq  = u - bp * NKQ;
    const int k0  = kq * KPU;
    const int ks  = tid >> 7;
    const int q   = tid & 127;
    const int o   = q >> 2;

    if (tid < KPU) actl[tid] = acts[bp * KTOT + k0 + tid];
    __syncthreads();

    for (int f = tid; f < KPU * O / 4; f += 256) {
        int kl = f >> 3;
        int kg = k0 + kl, kslot = kg >> 4;
        int kr = kslot / 3, kc = kslot - kr * 3;
        int p = bp % P2, pr = p / P, pc = p - pr * P;
        float ppc = (float)(npar(pr + kr) * npar(pc + kc));
        float r = actl[kl] / (ppc * 32.0f + EPSF);
        ((float4*)rrp)[f] = make_float4(r, r, r, r);
    }
    __syncthreads();

    const float* vb  = votes + (size_t)bp * VSZ + (size_t)(k0 + ks * 24) * 512 + q * 4;
    __half*      hb  = hv    + (size_t)bp * VSZ + (size_t)(k0 + ks * 24) * 512 + q * 4;
    const float* rr0 = rrp + (ks * 24) * O + o;
    float  s  = 0.f;
    float4 m1 = make_float4(0.f, 0.f, 0.f, 0.f);
    float4 m2 = make_float4(0.f, 0.f, 0.f, 0.f);

    float4 cur[8], nxt[8];
    #pragma unroll
    for (int j = 0; j < 8; ++j) cur[j] = *(const float4*)(vb + j * 512);

    #pragma unroll
    for (int ii = 0; ii < 3; ++ii) {
        if (ii < 2) {
            #pragma unroll
            for (int j = 0; j < 8; ++j)
                nxt[j] = *(const float4*)(vb + ((ii + 1) * 8 + j) * 512);
        }
        #pragma unroll
        for (int j = 0; j < 8; ++j) {
            float4 v = cur[j];
            float rp = rr0[(ii * 8 + j) * O];
            s += rp;
            m1.x += rp * v.x;       m1.y += rp * v.y;
            m1.z += rp * v.z;       m1.w += rp * v.w;
            m2.x += rp * v.x * v.x; m2.y += rp * v.y * v.y;
            m2.z += rp * v.z * v.z; m2.w += rp * v.w * v.w;
            __half2 ha  = __floats2half2_rn(v.x, v.y);
            __half2 hbv = __floats2half2_rn(v.z, v.w);
            uint2 st;
            st.x = *(unsigned int*)&ha;
            st.y = *(unsigned int*)&hbv;
            *(uint2*)(hb + (ii * 8 + j) * 512) = st;
        }
        #pragma unroll
        for (int j = 0; j < 8; ++j) cur[j] = nxt[j];
    }

    lm1[tid] = m1; lm2[tid] = m2; lss[tid] = s;
    __syncthreads();

    if (tid < 128) {
        float4 a = lm1[tid], b = lm1[tid + 128];
        m1 = make_float4(a.x + b.x, a.y + b.y, a.z + b.z, a.w + b.w);
        a = lm2[tid]; b = lm2[tid + 128];
        m2 = make_float4(a.x + b.x, a.y + b.y, a.z + b.z, a.w + b.w);
        s = lss[tid] + lss[tid + 128];
        ((float4*)g_m1)[u * 128 + tid] = m1;
        ((float4*)g_m2)[u * 128 + tid] = m2;
        if ((tid & 3) == 0) g_sv[u * O + (tid >> 2)] = s;
    }
}

// ---------------- S16: stats partials from fp16 votes ----------------
// 256 thr: tid = ks*64 + qp, qp = o*2 + h. MLP fix: all 12 uint4 preloaded.
__global__ __launch_bounds__(256)
void s16_kernel(const __half* __restrict__ hv, const float* __restrict__ acts)
{
    __shared__ float actl[KPU];
    __shared__ __align__(16) float rrp[KPU*O];
    __shared__ float4 lm1[512];
    __shared__ float4 lm2[512];
    __shared__ float  lss[256];

    const int tid = threadIdx.x;
    const int u   = blockIdx.x;
    const int bp  = u / NKQ;
    const int kq  = u - bp * NKQ;
    const int k0  = kq * KPU;
    const int ks  = tid >> 6;
    const int qp  = tid & 63;
    const int o   = qp >> 1;

    if (tid < KPU) actl[tid] = acts[bp * KTOT + k0 + tid];
    __syncthreads();

    for (int f = tid; f < KPU * O / 4; f += 256) {
        int kl = f >> 3;
        float4 r4 = ((const float4*)(g_rr + (size_t)bp * (KTOT * O) + k0 * O))[f];
        float a = actl[kl];
        r4.x *= a; r4.y *= a; r4.z *= a; r4.w *= a;
        ((float4*)rrp)[f] = r4;
    }
    __syncthreads();

    const __half* vb = hv + (size_t)bp * VSZ + (size_t)(k0 + ks * 12) * 512 + qp * 8;
    const float* rr0 = rrp + (ks * 12) * O + o;

    uint4 vv[12];
    #pragma unroll
    for (int i = 0; i < 12; ++i) vv[i] = *(const uint4*)(vb + i * 512);

    float s = 0.f;
    float m1[8], m2[8];
    #pragma unroll
    for (int j = 0; j < 8; ++j) { m1[j] = 0.f; m2[j] = 0.f; }
    #pragma unroll
    for (int i = 0; i < 12; ++i) {
        float rp = rr0[i * O];
        float f[8]; up8(vv[i], f);
        s += rp;
        #pragma unroll
        for (int j = 0; j < 8; ++j) {
            m1[j] += rp * f[j];
            m2[j] += rp * f[j] * f[j];
        }
    }
    lm1[tid*2]   = make_float4(m1[0], m1[1], m1[2], m1[3]);
    lm1[tid*2+1] = make_float4(m1[4], m1[5], m1[6], m1[7]);
    lm2[tid*2]   = make_float4(m2[0], m2[1], m2[2], m2[3]);
    lm2[tid*2+1] = make_float4(m2[4], m2[5], m2[6], m2[7]);
    lss[tid] = s;
    __syncthreads();

    if (tid < 64) {
        #pragma unroll
        for (int j = 0; j < 2; ++j) {
            float4 a0 = lm1[(tid)*2+j],       a1 = lm1[(64+tid)*2+j];
            float4 a2 = lm1[(128+tid)*2+j],   a3 = lm1[(192+tid)*2+j];
            float4 r = make_float4(a0.x+a1.x+a2.x+a3.x, a0.y+a1.y+a2.y+a3.y,
                                   a0.z+a1.z+a2.z+a3.z, a0.w+a1.w+a2.w+a3.w);
            ((float4*)g_m1)[u * 128 + tid*2 + j] = r;
            float4 b0 = lm2[(tid)*2+j],       b1 = lm2[(64+tid)*2+j];
            float4 b2 = lm2[(128+tid)*2+j],   b3 = lm2[(192+tid)*2+j];
            float4 r2 = make_float4(b0.x+b1.x+b2.x+b3.x, b0.y+b1.y+b2.y+b3.y,
                                    b0.z+b1.z+b2.z+b3.z, b0.w+b1.w+b2.w+b3.w);
            ((float4*)g_m2)[u * 128 + tid*2 + j] = r2;
        }
        float sr = lss[tid] + lss[64+tid] + lss[128+tid] + lss[192+tid];
        if ((tid & 1) == 0) g_sv[u * O + (tid >> 1)] = sr;
    }
}

// ---------------- shared finish computation (tid<128 path) ----------------
__device__ __forceinline__ void finish_bp(int bp, int tid, float lam,
                                          const float* __restrict__ beta_v,
                                          const float* __restrict__ beta_a,
                                          float4& mean, float4& i2,
                                          float& aj, float& lv2out,
                                          float* costl /* [O] LDS */)
{
    const int o = tid >> 2, c4 = tid & 3;
    float4 m1 = make_float4(0.f, 0.f, 0.f, 0.f);
    float4 m2 = make_float4(0.f, 0.f, 0.f, 0.f);
    float  s  = 0.f;
    #pragma unroll
    for (int j = 0; j < NKQ; ++j) {
        float4 a = ((const float4*)g_m1)[(bp * NKQ + j) * 128 + tid];
        float4 b = ((const float4*)g_m2)[(bp * NKQ + j) * 128 + tid];
        m1.x += a.x; m1.y += a.y; m1.z += a.z; m1.w += a.w;
        m2.x += b.x; m2.y += b.y; m2.z += b.z; m2.w += b.w;
        s += g_sv[(bp * NKQ + j) * O + o];
    }
    float denom = s + EPSF;
    mean = make_float4(m1.x / denom, m1.y / denom, m1.z / denom, m1.w / denom);
    float4 var;
    var.x = fmaxf(m2.x / denom - mean.x * mean.x, 1e-30f);
    var.y = fmaxf(m2.y / denom - mean.y * mean.y, 1e-30f);
    var.z = fmaxf(m2.z / denom - mean.z * mean.z, 1e-30f);
    var.w = fmaxf(m2.w / denom - mean.w * mean.w, 1e-30f);
    i2 = make_float4(0.5f / var.x, 0.5f / var.y, 0.5f / var.z, 0.5f / var.w);
    float lve = logf(var.x + EPSF) + logf(var.y + EPSF)
              + logf(var.z + EPSF) + logf(var.w + EPSF);
    float lv2 = logf(TWO_PI * var.x) + logf(TWO_PI * var.y)
              + logf(TWO_PI * var.z) + logf(TWO_PI * var.w);
    lve += __shfl_xor(lve, 1); lve += __shfl_xor(lve, 2);
    lv2 += __shfl_xor(lv2, 1); lv2 += __shfl_xor(lv2, 2);
    lv2out = lv2;
    if (c4 == 0) costl[o] = (16.f * beta_v[o] + 0.5f * lve) * s * LNF;
    __syncthreads();
    float cm = 0.f;
    #pragma unroll
    for (int i = 0; i < O; ++i) cm += costl[i];
    cm *= (1.f / 32.f);
    float sq = 0.f;
    #pragma unroll
    for (int i = 0; i < O; ++i) { float d = costl[i] - cm; sq += d * d; }
    float cstd = sqrtf(sq * (1.f / 32.f));
    aj = 1.f / (1.f + expf(-lam * (beta_a[o] + (cm - costl[o]) / (cstd + EPSF))));
}

// ---------------- ZF16: inline finish + zz from fp16 votes ----------------
__global__ __launch_bounds__(256)
void zf16_kernel(const __half* __restrict__ hv,
                 const float* __restrict__ beta_v,
                 const float* __restrict__ beta_a, float lam)
{
    __shared__ float4 ml[128];
    __shared__ float4 il[128];
    __shared__ float  zl[O];
    __shared__ float  costl[O];
    __shared__ __align__(16) float zzl[KPU*O];

    const int tid = threadIdx.x;
    const int u   = blockIdx.x;
    const int bp  = u / NKQ;
    const int kq  = u - bp * NKQ;
    const int k0  = kq * KPU;
    const int ks  = tid >> 6;
    const int qp  = tid & 63;
    const int o   = qp >> 1;
    const int h   = qp & 1;

    // issue the 12 vote loads FIRST (independent of the finish math)
    const __half* vb = hv + (size_t)bp * VSZ + (size_t)(k0 + ks * 12) * 512 + qp * 8;
    uint4 vv[12];
    #pragma unroll
    for (int i = 0; i < 12; ++i) vv[i] = *(const uint4*)(vb + i * 512);

    {
        float4 mean, i2; float aj, lv2;
        if (tid < 128) {
            finish_bp(bp, tid, lam, beta_v, beta_a, mean, i2, aj, lv2, costl);
            ml[tid] = mean; il[tid] = i2;
            if ((tid & 3) == 0)
                zl[tid >> 2] = logf(aj + EPSF) - 0.5f * lv2;
        } else {
            __syncthreads();   // matches the barrier inside finish_bp
        }
    }
    __syncthreads();

    float4 mA = ml[o*4 + h*2], mB = ml[o*4 + h*2 + 1];
    float4 iA = il[o*4 + h*2], iB = il[o*4 + h*2 + 1];
    float  zp = zl[o];
    #pragma unroll
    for (int i = 0; i < 12; ++i) {
        float f[8]; up8(vv[i], f);
        float d0 = f[0]-mA.x, d1 = f[1]-mA.y, d2 = f[2]-mA.z, d3 = f[3]-mA.w;
        float d4 = f[4]-mB.x, d5 = f[5]-mB.y, d6 = f[6]-mB.z, d7 = f[7]-mB.w;
        float t = d0*d0*iA.x + d1*d1*iA.y + d2*d2*iA.z + d3*d3*iA.w
                + d4*d4*iB.x + d5*d5*iB.y + d6*d6*iB.z + d7*d7*iB.w;
        t += __shfl_xor(t, 1);             // sum over 16 pose comps (h pair)
        if (h == 0) zzl[(ks * 12 + i) * O + o] = zp - t;
    }
    __syncthreads();
    float4* dst = (float4*)(g_zz + (size_t)bp * (KTOT * O) + k0 * O);
    for (int f = tid; f < KPU * O / 4; f += 256)
        dst[f] = ((float4*)zzl)[f];
}

// ---------------- F_last: finish + write outputs ----------------
__global__ __launch_bounds__(256)
void f_last_kernel(const float* __restrict__ beta_v,
                   const float* __restrict__ beta_a,
                   float* __restrict__ out, float lam)
{
    __shared__ float costl[O];
    const int tid = threadIdx.x;
    const int bp  = blockIdx.x;
    float4 mean, i2; float aj, lv2;
    if (tid < 128) {
        finish_bp(bp, tid, lam, beta_v, beta_a, mean, i2, aj, lv2, costl);
        ((float4*)out)[bp * 128 + tid] = mean;
        if ((tid & 3) == 0)
            out[(size_t)NBP * 512 + bp * O + (tid >> 2)] = aj;
    } else {
        __syncthreads();
    }
}

// ---------------- E: segment softmax ----------------
__global__ __launch_bounds__(256)
void e_kernel()
{
    const int tid = threadIdx.x;
    const int u   = blockIdx.x;
    const int b   = u / (CS * CS * 2);
    int r = u - b * (CS * CS * 2);
    const int child = r >> 1, half = r & 1;
    const int cr = child / CS, cl = child - cr * CS;
    const int cc = half * 8 + (tid >> 5), o = tid & 31;

    float zz[9];
    float vmax = -1e30f;
    #pragma unroll
    for (int kr = 0; kr < 3; ++kr) {
        int pr_ = cr - kr;
        #pragma unroll
        for (int kc = 0; kc < 3; ++kc) {
            int pc_ = cl - kc, si = kr * 3 + kc;
            float z = -1e30f;
            if (pr_ >= 0 && pr_ < P && pc_ >= 0 && pc_ < P) {
                int bpp = b * P2 + pr_ * P + pc_;
                z = g_zz[(size_t)bpp * (KTOT * O) + (si * CCAPS + cc) * O + o];
            }
            zz[si] = z;
            vmax = fmaxf(vmax, z);
        }
    }
    vmax = fmaxf(vmax, __shfl_xor(vmax, 1));
    vmax = fmaxf(vmax, __shfl_xor(vmax, 2));
    vmax = fmaxf(vmax, __shfl_xor(vmax, 4));
    vmax = fmaxf(vmax, __shfl_xor(vmax, 8));
    vmax = fmaxf(vmax, __shfl_xor(vmax, 16));

    float ps = 0.f;
    #pragma unroll
    for (int si = 0; si < 9; ++si) {
        float e = (zz[si] > -1e29f) ? expf(zz[si] - vmax) : 0.f;
        zz[si] = e;
        ps += e;
    }
    ps += __shfl_xor(ps, 1);
    ps += __shfl_xor(ps, 2);
    ps += __shfl_xor(ps, 4);
    ps += __shfl_xor(ps, 8);
    ps += __shfl_xor(ps, 16);
    float inv = 1.f / ps;

    #pragma unroll
    for (int kr = 0; kr < 3; ++kr) {
        int pr_ = cr - kr;
        #pragma unroll
        for (int kc = 0; kc < 3; ++kc) {
            int pc_ = cl - kc, si = kr * 3 + kc;
            if (pr_ >= 0 && pr_ < P && pc_ >= 0 && pc_ < P) {
                int bpp = b * P2 + pr_ * P + pc_;
                g_rr[(size_t)bpp * (KTOT * O) + (si * CCAPS + cc) * O + o] = zz[si] * inv;
            }
        }
    }
}

extern "C" void kernel_launch(void* const* d_in, const int* in_sizes, int n_in,
                              void* d_out, int out_size, void* d_ws, size_t ws_size,
                              hipStream_t stream)
{
    (void)in_sizes; (void)n_in; (void)out_size; (void)ws_size;

    const float* votes = (const float*)d_in[0];
    const float* acts  = (const float*)d_in[1];
    const float* bv    = (const float*)d_in[2];
    const float* ba    = (const float*)d_in[3];
    float* out = (float*)d_out;
    __half* hv = (__half*)d_ws;          // 59 MB fp16 votes copy

    dim3 t(256);
    v_kernel<<<dim3(SUNITS), t, 0, stream>>>(votes, acts, hv);
    zf16_kernel<<<dim3(SUNITS), t, 0, stream>>>(hv, bv, ba, LAM0);
    e_kernel<<<dim3(EUNITS), t, 0, stream>>>();

    s16_kernel<<<dim3(SUNITS), t, 0, stream>>>(hv, acts);
    zf16_kernel<<<dim3(SUNITS), t, 0, stream>>>(hv, bv, ba, LAM1);
    e_kernel<<<dim3(EUNITS), t, 0, stream>>>();

    s16_kernel<<<dim3(SUNITS), t, 0, stream>>>(hv, acts);
    f_last_kernel<<<dim3(NBP), t, 0, stream>>>(bv, ba, out, LAM2);
}